// Round 2
// baseline (220.646 us; speedup 1.0000x reference)
//
#include <hip/hip_runtime.h>
#include <stdint.h>

#define HIST1_SIZE 8192        // top 13 bits of (bits & 0x7fffffff) >> 18
#define HIST2_BITS 18
#define HIST2_SIZE 262144      // low 18 bits
#define HIST2_MASK (HIST2_SIZE - 1)
#define LIST_CAP 8192
#define MAX_SPIKE 36

// ws byte layout
#define WS_HIST1   0                       // 8192 * 4 = 32768
#define WS_SEL     32768                   // int[16]: b1,b2,cbase1,cbase2
#define WS_THRF    32832                   // float
#define WS_COUNTS  32840                   // int[4]: posE,posX,negE,negX
#define WS_TOTALS  32856                   // int[2]
#define WS_HIST2   65536                   // 2 * 262144 * 4 = 2097152
#define WS_LISTPE  2162688
#define WS_LISTPX  2195456
#define WS_LISTNE  2228224
#define WS_LISTNX  2260992
#define WS_PEAKSP  2293760
#define WS_PEAKSN  2326528
#define WS_ZERO_BYTES 2162688              // hist1 + scalars + hist2

__global__ __launch_bounds__(256) void k_hist1(const float* __restrict__ x, int N,
                                               int* __restrict__ hist1) {
  __shared__ int h[HIST1_SIZE];
  for (int i = threadIdx.x; i < HIST1_SIZE; i += 256) h[i] = 0;
  __syncthreads();
  int NV = N >> 2;
  int stride = gridDim.x * 256;
  for (int j = blockIdx.x * 256 + threadIdx.x; j < NV; j += stride) {
    float4 v = reinterpret_cast<const float4*>(x)[j];
    atomicAdd(&h[(__float_as_uint(v.x) & 0x7fffffffu) >> HIST2_BITS], 1);
    atomicAdd(&h[(__float_as_uint(v.y) & 0x7fffffffu) >> HIST2_BITS], 1);
    atomicAdd(&h[(__float_as_uint(v.z) & 0x7fffffffu) >> HIST2_BITS], 1);
    atomicAdd(&h[(__float_as_uint(v.w) & 0x7fffffffu) >> HIST2_BITS], 1);
  }
  if (blockIdx.x == 0 && threadIdx.x == 0) {          // tail (N % 4)
    for (int i = NV << 2; i < N; ++i)
      atomicAdd(&h[(__float_as_uint(x[i]) & 0x7fffffffu) >> HIST2_BITS], 1);
  }
  __syncthreads();
  for (int i = threadIdx.x; i < HIST1_SIZE; i += 256) {
    int c = h[i];
    if (c) atomicAdd(&hist1[i], c);
  }
}

// find buckets containing ranks k1,k2 -> sel[0..3] = b1, b2, cbase1, cbase2
__global__ void k_select(const int* __restrict__ hist1, long long k1, long long k2,
                         int* __restrict__ sel) {
  __shared__ int part[256];
  __shared__ long long excl[256];
  int tid = threadIdx.x;
  const int chunk = HIST1_SIZE / 256;  // 32
  int base = tid * chunk;
  int s = 0;
  for (int w = 0; w < chunk; ++w) s += hist1[base + w];
  part[tid] = s;
  __syncthreads();
  if (tid == 0) {
    long long acc = 0;
    for (int i = 0; i < 256; ++i) { excl[i] = acc; acc += part[i]; }
  }
  __syncthreads();
  long long pre = excl[tid];
  if (pre <= k1 && k1 < pre + part[tid]) {
    long long acc = pre;
    for (int w = 0; w < chunk; ++w) {
      int c = hist1[base + w];
      if (k1 < acc + c) { sel[0] = base + w; sel[2] = (int)acc; break; }
      acc += c;
    }
  }
  if (pre <= k2 && k2 < pre + part[tid]) {
    long long acc = pre;
    for (int w = 0; w < chunk; ++w) {
      int c = hist1[base + w];
      if (k2 < acc + c) { sel[1] = base + w; sel[3] = (int)acc; break; }
      acc += c;
    }
  }
}

__global__ __launch_bounds__(256) void k_refine(const float* __restrict__ x, int N,
                                                const int* __restrict__ sel,
                                                int* __restrict__ hist2) {
  int b1 = sel[0], b2 = sel[1];
  int NV = N >> 2;
  int stride = gridDim.x * 256;
  for (int j = blockIdx.x * 256 + threadIdx.x; j < NV; j += stride) {
    float4 v = reinterpret_cast<const float4*>(x)[j];
    uint32_t u;
    u = __float_as_uint(v.x) & 0x7fffffffu;
    if ((int)(u >> HIST2_BITS) == b1) atomicAdd(&hist2[u & HIST2_MASK], 1);
    else if ((int)(u >> HIST2_BITS) == b2) atomicAdd(&hist2[HIST2_SIZE + (u & HIST2_MASK)], 1);
    u = __float_as_uint(v.y) & 0x7fffffffu;
    if ((int)(u >> HIST2_BITS) == b1) atomicAdd(&hist2[u & HIST2_MASK], 1);
    else if ((int)(u >> HIST2_BITS) == b2) atomicAdd(&hist2[HIST2_SIZE + (u & HIST2_MASK)], 1);
    u = __float_as_uint(v.z) & 0x7fffffffu;
    if ((int)(u >> HIST2_BITS) == b1) atomicAdd(&hist2[u & HIST2_MASK], 1);
    else if ((int)(u >> HIST2_BITS) == b2) atomicAdd(&hist2[HIST2_SIZE + (u & HIST2_MASK)], 1);
    u = __float_as_uint(v.w) & 0x7fffffffu;
    if ((int)(u >> HIST2_BITS) == b1) atomicAdd(&hist2[u & HIST2_MASK], 1);
    else if ((int)(u >> HIST2_BITS) == b2) atomicAdd(&hist2[HIST2_SIZE + (u & HIST2_MASK)], 1);
  }
  if (blockIdx.x == 0 && threadIdx.x == 0) {
    for (int i = NV << 2; i < N; ++i) {
      uint32_t u = __float_as_uint(x[i]) & 0x7fffffffu;
      if ((int)(u >> HIST2_BITS) == b1) atomicAdd(&hist2[u & HIST2_MASK], 1);
      else if ((int)(u >> HIST2_BITS) == b2) atomicAdd(&hist2[HIST2_SIZE + (u & HIST2_MASK)], 1);
    }
  }
}

// exact order stats -> median -> threshold (match reference float32 arithmetic)
__global__ void k_thresh(const int* __restrict__ hist2, const int* __restrict__ sel,
                         long long k1, long long k2,
                         float* __restrict__ thrF) {
  __shared__ int part[256];
  __shared__ long long excl[256];
  __shared__ int resBin;
  __shared__ float vres[2];
  int tid = threadIdx.x;
  int b1 = sel[0], b2 = sel[1];
  long long r1 = k1 - sel[2];
  long long r2 = k2 - ((b2 == b1) ? sel[2] : sel[3]);
  const int* hB = (b2 == b1) ? hist2 : (hist2 + HIST2_SIZE);
  for (int pass = 0; pass < 2; ++pass) {
    const int* hh = pass ? hB : hist2;
    long long kk = pass ? r2 : r1;
    const int chunk = HIST2_SIZE / 256;  // 1024
    int base = tid * chunk;
    int s = 0;
    for (int w = 0; w < chunk; ++w) s += hh[base + w];
    part[tid] = s;
    __syncthreads();
    if (tid == 0) {
      long long acc = 0;
      for (int i = 0; i < 256; ++i) { excl[i] = acc; acc += part[i]; }
    }
    __syncthreads();
    long long pre = excl[tid];
    if (pre <= kk && kk < pre + part[tid]) {
      long long acc = pre;
      for (int w = 0; w < chunk; ++w) {
        int c = hh[base + w];
        if (kk < acc + c) { resBin = base + w; break; }
        acc += c;
      }
    }
    __syncthreads();
    if (tid == 0) {
      int bb = pass ? b2 : b1;
      vres[pass] = __uint_as_float(((uint32_t)bb << HIST2_BITS) | (uint32_t)resBin);
    }
    __syncthreads();
  }
  if (tid == 0) {
    float med = 0.5f * (vres[0] + vres[1]);     // np.median: mean of two mid order stats
    float thr = (5.0f * med) / 0.6745f;         // reference float32 expression order
    *thrF = thr;
  }
}

__global__ __launch_bounds__(256) void k_detect(const float* __restrict__ x, int N,
                                                const float* __restrict__ thrF,
                                                int* __restrict__ counts,
                                                int* __restrict__ pe, int* __restrict__ px,
                                                int* __restrict__ ne, int* __restrict__ nx) {
  float thr = *thrF;
  float nthr = -thr;
  int NV = N >> 2;
  int stride = gridDim.x * 256;
  for (int j = blockIdx.x * 256 + threadIdx.x; j < NV; j += stride) {
    float4 v = reinterpret_cast<const float4*>(x)[j];
    int base = j << 2;
    float arr[5];
    arr[0] = v.x; arr[1] = v.y; arr[2] = v.z; arr[3] = v.w;
    arr[4] = (base + 4 < N) ? x[base + 4] : v.w;
#pragma unroll
    for (int t = 0; t < 4; ++t) {
      int p = base + t;
      if (p < N - 1) {
        bool m0 = arr[t] > thr, m1 = arr[t + 1] > thr;
        if (m0 != m1) {
          if (m1) { int id = atomicAdd(&counts[0], 1); if (id < LIST_CAP) pe[id] = p; }
          else    { int id = atomicAdd(&counts[1], 1); if (id < LIST_CAP) px[id] = p; }
        }
        bool n0 = arr[t] < nthr, n1 = arr[t + 1] < nthr;
        if (n0 != n1) {
          if (n1) { int id = atomicAdd(&counts[2], 1); if (id < LIST_CAP) ne[id] = p; }
          else    { int id = atomicAdd(&counts[3], 1); if (id < LIST_CAP) nx[id] = p; }
        }
      }
    }
  }
  if (blockIdx.x == 0 && threadIdx.x == 0) {     // tail positions [4*NV, N-2]
    for (int p = NV << 2; p < N - 1; ++p) {
      float a = x[p], b = x[p + 1];
      bool m0 = a > thr, m1 = b > thr;
      if (m0 != m1) {
        if (m1) { int id = atomicAdd(&counts[0], 1); if (id < LIST_CAP) pe[id] = p; }
        else    { int id = atomicAdd(&counts[1], 1); if (id < LIST_CAP) px[id] = p; }
      }
      bool n0 = a < nthr, n1 = b < nthr;
      if (n0 != n1) {
        if (n1) { int id = atomicAdd(&counts[2], 1); if (id < LIST_CAP) ne[id] = p; }
        else    { int id = atomicAdd(&counts[3], 1); if (id < LIST_CAP) nx[id] = p; }
      }
    }
  }
}

__device__ static void isort(int* a, int n) {
  for (int i = 1; i < n; ++i) {
    int v = a[i]; int j = i - 1;
    while (j >= 0 && a[j] > v) { a[j + 1] = a[j]; --j; }
    a[j + 1] = v;
  }
}

__device__ static void proc_one(const float* x, int N, int sign,
                                int* eL, int nE, int* xL, int nX,
                                int* outPeaks, int* total) {
  isort(eL, nE);
  isort(xL, nX);
  int n = nE < nX ? nE : nX;
  int tot = 0;
  for (int t = 0; t < n; ++t) {
    int dur = xL[t] - eL[t];
    if (dur <= MAX_SPIKE) {                    // negative dur also kept (ref semantics)
      int e = eL[t];
      float best = -INFINITY; int bi = 0;
      for (int w = 0; w < MAX_SPIKE; ++w) {
        int idx = e + w; if (idx > N - 1) idx = N - 1;
        float val = x[idx]; if (sign < 0) val = -val;
        if (val > best) { best = val; bi = w; } // first occurrence of max
      }
      if (tot < LIST_CAP) outPeaks[tot] = e + bi;
      ++tot;
    }
  }
  if (tot > LIST_CAP) tot = LIST_CAP;
  isort(outPeaks, tot);                        // ref sorts peaks
  *total = tot;
}

__global__ void k_finalize(const float* __restrict__ x, int N,
                           const int* __restrict__ counts,
                           int* pe, int* px, int* ne, int* nx,
                           int* peaksP, int* peaksN, int* totals) {
  if (threadIdx.x != 0 || blockIdx.x != 0) return;
  int nPE = counts[0] < LIST_CAP ? counts[0] : LIST_CAP;
  int nPX = counts[1] < LIST_CAP ? counts[1] : LIST_CAP;
  int nNE = counts[2] < LIST_CAP ? counts[2] : LIST_CAP;
  int nNX = counts[3] < LIST_CAP ? counts[3] : LIST_CAP;
  proc_one(x, N, +1, pe, nPE, px, nPX, peaksP, &totals[0]);
  proc_one(x, N, -1, ne, nNE, nx, nNX, peaksN, &totals[1]);
}

// d_out is a float32 buffer (mixed-dtype tuple => harness reads float32):
// [OUT_K pos idx][OUT_K neg idx][threshold], indices as floats, -1.0f pad.
__global__ __launch_bounds__(256) void k_fill(float* __restrict__ out, int OUT_K,
                                              const int* __restrict__ peaksP,
                                              const int* __restrict__ peaksN,
                                              const int* __restrict__ totals,
                                              const float* __restrict__ thrF) {
  int j = blockIdx.x * 256 + threadIdx.x;
  if (j >= 2 * OUT_K + 1) return;
  if (j < OUT_K) {
    out[j] = (j < totals[0]) ? (float)peaksP[j] : -1.0f;
  } else if (j < 2 * OUT_K) {
    int jj = j - OUT_K;
    out[j] = (jj < totals[1]) ? (float)peaksN[jj] : -1.0f;
  } else {
    out[j] = *thrF;
  }
}

extern "C" void kernel_launch(void* const* d_in, const int* in_sizes, int n_in,
                              void* d_out, int out_size, void* d_ws, size_t ws_size,
                              hipStream_t stream) {
  const float* x = (const float*)d_in[0];
  int N = in_sizes[0];
  float* out = (float*)d_out;
  char* ws = (char*)d_ws;

  int* hist1  = (int*)(ws + WS_HIST1);
  int* sel    = (int*)(ws + WS_SEL);
  float* thrF = (float*)(ws + WS_THRF);
  int* counts = (int*)(ws + WS_COUNTS);
  int* totals = (int*)(ws + WS_TOTALS);
  int* hist2  = (int*)(ws + WS_HIST2);
  int* listPE = (int*)(ws + WS_LISTPE);
  int* listPX = (int*)(ws + WS_LISTPX);
  int* listNE = (int*)(ws + WS_LISTNE);
  int* listNX = (int*)(ws + WS_LISTNX);
  int* peaksP = (int*)(ws + WS_PEAKSP);
  int* peaksN = (int*)(ws + WS_PEAKSN);

  hipMemsetAsync(d_ws, 0, WS_ZERO_BYTES, stream);

  long long k1 = (long long)(N / 2) - 1;
  long long k2 = (long long)(N / 2);

  k_hist1<<<1024, 256, 0, stream>>>(x, N, hist1);
  k_select<<<1, 256, 0, stream>>>(hist1, k1, k2, sel);
  k_refine<<<2048, 256, 0, stream>>>(x, N, sel, hist2);
  k_thresh<<<1, 256, 0, stream>>>(hist2, sel, k1, k2, thrF);
  k_detect<<<2048, 256, 0, stream>>>(x, N, thrF, counts, listPE, listPX, listNE, listNX);
  k_finalize<<<1, 64, 0, stream>>>(x, N, counts, listPE, listPX, listNE, listNX,
                                   peaksP, peaksN, totals);
  int OUT_K = (out_size - 1) / 2;  // 65536
  k_fill<<<(2 * OUT_K + 1 + 255) / 256, 256, 0, stream>>>(out, OUT_K, peaksP, peaksN,
                                                          totals, thrF);
}

// Round 3
// 193.152 us; speedup vs baseline: 1.1423x; 1.1423x over previous
//
#include <hip/hip_runtime.h>
#include <stdint.h>

#define HIST2_BITS 18
#define HIST1_SIZE 8192        // top 13 bits of (bits & 0x7fffffff)
#define HIST2_SIZE 262144      // low 18 bits
#define HIST2_MASK (HIST2_SIZE - 1)
#define COARSE_SIZE 1024       // fine bin >> 8
#define CAND_CAP 8192
#define PAIR_CAP 1024
#define PEAK_CAP 512
#define MAX_SPIKE 36

// ws byte layout (zeroed region first)
#define WS_HIST1   0                       // 8192*4 = 32768
#define WS_COARSE  32768                   // 2*1024*4 = 8192 -> 40960
#define WS_SEL     40960                   // int[4]: b1,b2,cbase1,cbase2
#define WS_THRLO   40976                   // float
#define WS_THRF    40980                   // float
#define WS_CANDN   40984                   // int
#define WS_HIST2   65536                   // 2*262144*4 = 2097152 -> 2162688
#define WS_ZERO_BYTES 2162688
#define WS_CAND    2162688                 // 8192*4 -> 2195456
#define WS_PEAKSP  2195456                 // 512*4  -> 2197504
#define WS_PEAKSN  2197504                 // 512*4  -> 2199552
#define WS_TOTALS  2199552                 // int[2]

// ---------------- pass 1: coarse 13-bit histogram of abs bit patterns ----------------
__global__ __launch_bounds__(256) void k_hist1(const float* __restrict__ x, int N,
                                               int* __restrict__ hist1) {
  __shared__ int h[HIST1_SIZE];
  for (int i = threadIdx.x; i < HIST1_SIZE; i += 256) h[i] = 0;
  __syncthreads();
  int NV = N >> 2;
  int stride = gridDim.x * 256;
  for (int j = blockIdx.x * 256 + threadIdx.x; j < NV; j += stride) {
    float4 v = reinterpret_cast<const float4*>(x)[j];
    atomicAdd(&h[(__float_as_uint(v.x) & 0x7fffffffu) >> HIST2_BITS], 1);
    atomicAdd(&h[(__float_as_uint(v.y) & 0x7fffffffu) >> HIST2_BITS], 1);
    atomicAdd(&h[(__float_as_uint(v.z) & 0x7fffffffu) >> HIST2_BITS], 1);
    atomicAdd(&h[(__float_as_uint(v.w) & 0x7fffffffu) >> HIST2_BITS], 1);
  }
  if (blockIdx.x == 0 && threadIdx.x == 0) {          // tail (N % 4)
    for (int i = NV << 2; i < N; ++i)
      atomicAdd(&h[(__float_as_uint(x[i]) & 0x7fffffffu) >> HIST2_BITS], 1);
  }
  __syncthreads();
  for (int i = threadIdx.x; i < HIST1_SIZE; i += 256) {
    int c = h[i];
    if (c) atomicAdd(&hist1[i], c);
  }
}

// ---------------- select buckets of ranks k1,k2; emit conservative thrLo ----------------
__global__ void k_select(const int* __restrict__ hist1, long long k1, long long k2,
                         int* __restrict__ sel, float* __restrict__ thrLoP) {
  __shared__ int part[256];
  __shared__ long long excl[256];
  int tid = threadIdx.x;
  const int chunk = HIST1_SIZE / 256;  // 32
  int base = tid * chunk;
  int s = 0;
  for (int w = 0; w < chunk; ++w) s += hist1[base + w];
  part[tid] = s;
  __syncthreads();
  if (tid == 0) {
    long long acc = 0;
    for (int i = 0; i < 256; ++i) { excl[i] = acc; acc += part[i]; }
  }
  __syncthreads();
  long long pre = excl[tid];
  if (pre <= k1 && k1 < pre + part[tid]) {
    long long acc = pre;
    for (int w = 0; w < chunk; ++w) {
      int c = hist1[base + w];
      if (k1 < acc + c) { sel[0] = base + w; sel[2] = (int)acc; break; }
      acc += c;
    }
  }
  if (pre <= k2 && k2 < pre + part[tid]) {
    long long acc = pre;
    for (int w = 0; w < chunk; ++w) {
      int c = hist1[base + w];
      if (k2 < acc + c) { sel[1] = base + w; sel[3] = (int)acc; break; }
      acc += c;
    }
  }
  __syncthreads();
  if (tid == 0) {
    // conservative lower bound on threshold from bucket lower edges
    float lo1 = __uint_as_float((uint32_t)sel[0] << HIST2_BITS);
    float lo2 = __uint_as_float((uint32_t)sel[1] << HIST2_BITS);
    float mLo = 0.5f * (lo1 + lo2);
    *thrLoP = (5.0f * mLo / 0.6745f) * 0.999f;
  }
}

// ---------------- pass 2: fine+coarse hist of median buckets AND candidate elements ----------------
__global__ __launch_bounds__(256) void k_pass2(const float* __restrict__ x, int N,
                                               const int* __restrict__ sel,
                                               const float* __restrict__ thrLoP,
                                               int* __restrict__ hist2,
                                               int* __restrict__ coarse,
                                               int* __restrict__ candN,
                                               int* __restrict__ cand) {
  int b1 = sel[0], b2 = sel[1];
  float thrLo = *thrLoP;
  int NV = N >> 2;
  int stride = gridDim.x * 256;
  for (int j = blockIdx.x * 256 + threadIdx.x; j < NV; j += stride) {
    float4 v = reinterpret_cast<const float4*>(x)[j];
    int base = j << 2;
#pragma unroll
    for (int t = 0; t < 4; ++t) {
      float f = (t == 0) ? v.x : (t == 1) ? v.y : (t == 2) ? v.z : v.w;
      uint32_t u = __float_as_uint(f) & 0x7fffffffu;
      int top = (int)(u >> HIST2_BITS);
      if (top == b1) {
        atomicAdd(&hist2[u & HIST2_MASK], 1);
        atomicAdd(&coarse[(u & HIST2_MASK) >> 8], 1);
      } else if (top == b2) {
        atomicAdd(&hist2[HIST2_SIZE + (u & HIST2_MASK)], 1);
        atomicAdd(&coarse[COARSE_SIZE + ((u & HIST2_MASK) >> 8)], 1);
      }
      if (__uint_as_float(u) > thrLo) {          // |f| > thrLo
        int id = atomicAdd(candN, 1);
        if (id < CAND_CAP) cand[id] = base + t;
      }
    }
  }
  if (blockIdx.x == 0 && threadIdx.x == 0) {      // tail (N % 4)
    for (int i = NV << 2; i < N; ++i) {
      float f = x[i];
      uint32_t u = __float_as_uint(f) & 0x7fffffffu;
      int top = (int)(u >> HIST2_BITS);
      if (top == b1) {
        atomicAdd(&hist2[u & HIST2_MASK], 1);
        atomicAdd(&coarse[(u & HIST2_MASK) >> 8], 1);
      } else if (top == b2) {
        atomicAdd(&hist2[HIST2_SIZE + (u & HIST2_MASK)], 1);
        atomicAdd(&coarse[COARSE_SIZE + ((u & HIST2_MASK) >> 8)], 1);
      }
      if (__uint_as_float(u) > thrLo) {
        int id = atomicAdd(candN, 1);
        if (id < CAND_CAP) cand[id] = i;
      }
    }
  }
}

// ---------------- exact order stats via coarse->fine parallel scan ----------------
__global__ void k_thresh2(const int* __restrict__ hist2, const int* __restrict__ coarse,
                          const int* __restrict__ sel, long long k1, long long k2,
                          float* __restrict__ thrF) {
  __shared__ int sh[256];
  __shared__ long long excl[256];
  __shared__ int resG;
  __shared__ long long resPre;
  __shared__ float vres[2];
  int tid = threadIdx.x;  // 256 threads
  for (int pass = 0; pass < 2; ++pass) {
    __syncthreads();
    bool sameB = (sel[1] == sel[0]);
    bool second = (pass == 1) && !sameB;
    const int* ch = coarse + (second ? COARSE_SIZE : 0);
    const int* hh = hist2 + (second ? HIST2_SIZE : 0);
    long long kk = (pass == 0) ? (k1 - sel[2]) : (k2 - (sameB ? sel[2] : sel[3]));
    // coarse stage: 1024 entries, 4 per thread
    int c0 = ch[tid * 4], c1 = ch[tid * 4 + 1], c2 = ch[tid * 4 + 2], c3 = ch[tid * 4 + 3];
    sh[tid] = c0 + c1 + c2 + c3;
    __syncthreads();
    if (tid == 0) {
      long long a = 0;
      for (int i = 0; i < 256; ++i) { excl[i] = a; a += sh[i]; }
    }
    __syncthreads();
    long long pre = excl[tid];
    if (pre <= kk && kk < pre + (long long)sh[tid]) {
      long long a = pre;
      int cc[4] = {c0, c1, c2, c3};
      for (int w = 0; w < 4; ++w) {
        if (kk < a + cc[w]) { resG = tid * 4 + w; resPre = a; break; }
        a += cc[w];
      }
    }
    __syncthreads();
    int g = resG;
    long long kf = kk - resPre;
    // fine stage: 256 bins of group g
    int fcnt = hh[g * 256 + tid];
    __syncthreads();
    sh[tid] = fcnt;
    __syncthreads();
    if (tid == 0) {
      long long a = 0;
      for (int i = 0; i < 256; ++i) { excl[i] = a; a += sh[i]; }
    }
    __syncthreads();
    pre = excl[tid];
    if (pre <= kf && kf < pre + (long long)fcnt) {
      int bb = (pass == 0) ? sel[0] : sel[1];
      vres[pass] = __uint_as_float(((uint32_t)bb << HIST2_BITS) | (uint32_t)(g * 256 + tid));
    }
    __syncthreads();
  }
  if (tid == 0) {
    float med = 0.5f * (vres[0] + vres[1]);     // np.median: mean of two mid order stats
    *thrF = (5.0f * med) / 0.6745f;             // reference float32 expression order
  }
}

// ---------------- finalize: pairs from candidates, windowed argmax, sort ----------------
__device__ static void isort(int* a, int n) {
  for (int i = 1; i < n; ++i) {
    int v = a[i]; int j = i - 1;
    while (j >= 0 && a[j] > v) { a[j + 1] = a[j]; --j; }
    a[j + 1] = v;
  }
}

__device__ inline void eval_pair(const float* __restrict__ x, int p, float thr,
                                 int* pe, int* px, int* ne, int* nx, int* cnt) {
  float a = x[p], b = x[p + 1];
  bool m0 = a > thr, m1 = b > thr;
  if (m0 != m1) {
    int id = atomicAdd(&cnt[m1 ? 0 : 1], 1);
    if (id < PAIR_CAP) (m1 ? pe : px)[id] = p;
  }
  bool q0 = (-a) > thr, q1 = (-b) > thr;       // exact ref form: v=-x, v>thr
  if (q0 != q1) {
    int id = atomicAdd(&cnt[q1 ? 2 : 3], 1);
    if (id < PAIR_CAP) (q1 ? ne : nx)[id] = p;
  }
}

__device__ inline int wave_argmax36(const float* __restrict__ x, int N, int sign,
                                    int e, int lane) {
  float val = -INFINITY;
  int wi = lane;
  if (lane < MAX_SPIKE) {
    int idx = e + lane; if (idx > N - 1) idx = N - 1;   // ref: clip(entry+w, 0, N-1)
    float v = x[idx];
    val = (sign < 0) ? -v : v;
  }
  for (int off = 32; off; off >>= 1) {                  // tie -> smaller w (first max)
    float ov = __shfl_xor(val, off);
    int owi = __shfl_xor(wi, off);
    if (ov > val || (ov == val && owi < wi)) { val = ov; wi = owi; }
  }
  return e + wi;
}

__device__ inline int proc_pol(const float* __restrict__ x, int N, int sign,
                               const int* eL, int nE, const int* xL, int nX,
                               int* pk, int tid) {
  int n = nE < nX ? nE : nX;
  int tot = 0;
  for (int t = 0; t < n; ++t) {
    int dur = xL[t] - eL[t];
    if (dur <= MAX_SPIKE) {                    // negative dur kept (ref semantics)
      int p = wave_argmax36(x, N, sign, eL[t], tid);
      if (tot < PEAK_CAP && tid == 0) pk[tot] = p;
      ++tot;
    }
  }
  if (tot > PEAK_CAP) tot = PEAK_CAP;
  if (tid == 0) isort(pk, tot);                // ref sorts peaks
  return tot;
}

__global__ void k_finalize(const float* __restrict__ x, int N,
                           const float* __restrict__ thrFP,
                           const int* __restrict__ candNP, int* __restrict__ cand,
                           int* __restrict__ peaksP, int* __restrict__ peaksN,
                           int* __restrict__ totals) {
  __shared__ int pe[PAIR_CAP], px[PAIR_CAP], ne[PAIR_CAP], nx[PAIR_CAP];
  __shared__ int cnt[4];
  __shared__ int pkP[PEAK_CAP], pkN[PEAK_CAP];
  __shared__ int nPk[2];
  int tid = threadIdx.x;                        // blockDim = 64 (one wave)
  float thr = *thrFP;
  int nC = *candNP; if (nC > CAND_CAP) nC = CAND_CAP;
  if (tid < 4) cnt[tid] = 0;
  __syncthreads();
  if (tid == 0) isort(cand, nC);                // sort candidate indices
  __syncthreads();
  // build crossing pairs in parallel; pair (p,p+1) processed exactly once:
  // from candidate p (right pair), or from candidate p+1 iff p not candidate.
  for (int k = tid; k < nC; k += 64) {
    int c = cand[k];
    bool prevAdj = (k > 0) && (cand[k - 1] == c - 1);
    if (c > 0 && !prevAdj) eval_pair(x, c - 1, thr, pe, px, ne, nx, cnt);
    if (c <= N - 2) eval_pair(x, c, thr, pe, px, ne, nx, cnt);
  }
  __syncthreads();
  int nPE = min(cnt[0], PAIR_CAP), nPX = min(cnt[1], PAIR_CAP);
  int nNE = min(cnt[2], PAIR_CAP), nNX = min(cnt[3], PAIR_CAP);
  if (tid == 0) { isort(pe, nPE); isort(px, nPX); }
  else if (tid == 1) { isort(ne, nNE); isort(nx, nNX); }
  __syncthreads();
  int t0 = proc_pol(x, N, +1, pe, nPE, px, nPX, pkP, tid);
  int t1 = proc_pol(x, N, -1, ne, nNE, nx, nNX, pkN, tid);
  if (tid == 0) { nPk[0] = t0; nPk[1] = t1; totals[0] = t0; totals[1] = t1; }
  __syncthreads();
  for (int j = tid; j < nPk[0]; j += 64) peaksP[j] = pkP[j];
  for (int j = tid; j < nPk[1]; j += 64) peaksN[j] = pkN[j];
}

// d_out is a float32 buffer: [OUT_K pos idx][OUT_K neg idx][threshold], -1.0f pad.
__global__ __launch_bounds__(256) void k_fill(float* __restrict__ out, int OUT_K,
                                              const int* __restrict__ peaksP,
                                              const int* __restrict__ peaksN,
                                              const int* __restrict__ totals,
                                              const float* __restrict__ thrF) {
  int j = blockIdx.x * 256 + threadIdx.x;
  if (j >= 2 * OUT_K + 1) return;
  if (j < OUT_K) {
    out[j] = (j < totals[0]) ? (float)peaksP[j] : -1.0f;
  } else if (j < 2 * OUT_K) {
    int jj = j - OUT_K;
    out[j] = (jj < totals[1]) ? (float)peaksN[jj] : -1.0f;
  } else {
    out[j] = *thrF;
  }
}

extern "C" void kernel_launch(void* const* d_in, const int* in_sizes, int n_in,
                              void* d_out, int out_size, void* d_ws, size_t ws_size,
                              hipStream_t stream) {
  const float* x = (const float*)d_in[0];
  int N = in_sizes[0];
  float* out = (float*)d_out;
  char* ws = (char*)d_ws;

  int* hist1   = (int*)(ws + WS_HIST1);
  int* coarse  = (int*)(ws + WS_COARSE);
  int* sel     = (int*)(ws + WS_SEL);
  float* thrLo = (float*)(ws + WS_THRLO);
  float* thrF  = (float*)(ws + WS_THRF);
  int* candN   = (int*)(ws + WS_CANDN);
  int* hist2   = (int*)(ws + WS_HIST2);
  int* cand    = (int*)(ws + WS_CAND);
  int* peaksP  = (int*)(ws + WS_PEAKSP);
  int* peaksN  = (int*)(ws + WS_PEAKSN);
  int* totals  = (int*)(ws + WS_TOTALS);

  hipMemsetAsync(d_ws, 0, WS_ZERO_BYTES, stream);

  long long k1 = (long long)(N / 2) - 1;
  long long k2 = (long long)(N / 2);

  k_hist1<<<2048, 256, 0, stream>>>(x, N, hist1);
  k_select<<<1, 256, 0, stream>>>(hist1, k1, k2, sel, thrLo);
  k_pass2<<<2048, 256, 0, stream>>>(x, N, sel, thrLo, hist2, coarse, candN, cand);
  k_thresh2<<<1, 256, 0, stream>>>(hist2, coarse, sel, k1, k2, thrF);
  k_finalize<<<1, 64, 0, stream>>>(x, N, thrF, candN, cand, peaksP, peaksN, totals);
  int OUT_K = (out_size - 1) / 2;  // 65536
  k_fill<<<(2 * OUT_K + 1 + 255) / 256, 256, 0, stream>>>(out, OUT_K, peaksP, peaksN,
                                                          totals, thrF);
}

// Round 4
// 151.249 us; speedup vs baseline: 1.4588x; 1.2770x over previous
//
#include <hip/hip_runtime.h>
#include <stdint.h>

#define HIST2_BITS 18
#define HIST1_SIZE 8192        // top 13 bits of (bits & 0x7fffffff)
#define LOW18_MASK 0x3FFFF
#define CAND_CAP 8192
#define LIST_CAP 1500000
#define LBUF_CAP 3072
#define PAIR_CAP 1024
#define PEAK_CAP 512
#define MAX_SPIKE 36

// params indices (int array)
#define P_B1    0
#define P_B2    1
#define P_R1    2
#define P_R2    3
#define P_THRLO 4
#define P_THR   5
#define P_CANDN 6
#define P_LISTN 7
#define P_BINA0 8
#define P_BINA1 9
#define P_RA0   10
#define P_RA1   11
#define P_TAG1  12

// ws byte layout
#define WS_HIST1   0                 // 32768
#define WS_HISTA   32768             // 2*1024*4 = 8192 -> 40960
#define WS_HISTB   40960             // 2*256*4  = 2048 -> 43008
#define WS_PARAMS  43008             // 64 -> 43072
#define WS_TOTALS  43072             // 8  -> 43080
#define WS_ZERO_BYTES 43080
#define WS_CAND    65536             // 8192*4 -> 98304
#define WS_PEAKSP  98304             // 2048 -> 100352
#define WS_PEAKSN  100352            // 2048 -> 102400
#define WS_LIST    102400            // 1.5M*4 = 6MB

// ---------------- pass 1: 13-bit histogram of abs bit patterns ----------------
__global__ __launch_bounds__(256) void k_hist1(const float* __restrict__ x, int N,
                                               int* __restrict__ hist1) {
  __shared__ int h[HIST1_SIZE];
  for (int i = threadIdx.x; i < HIST1_SIZE; i += 256) h[i] = 0;
  __syncthreads();
  int NV = N >> 2;
  int str = gridDim.x * 256;
  int j = blockIdx.x * 256 + threadIdx.x;
  const float4* vec = reinterpret_cast<const float4*>(x);
  for (; j + str < NV; j += 2 * str) {
    float4 a = vec[j];
    float4 b = vec[j + str];
    atomicAdd(&h[(__float_as_uint(a.x) & 0x7fffffffu) >> HIST2_BITS], 1);
    atomicAdd(&h[(__float_as_uint(a.y) & 0x7fffffffu) >> HIST2_BITS], 1);
    atomicAdd(&h[(__float_as_uint(a.z) & 0x7fffffffu) >> HIST2_BITS], 1);
    atomicAdd(&h[(__float_as_uint(a.w) & 0x7fffffffu) >> HIST2_BITS], 1);
    atomicAdd(&h[(__float_as_uint(b.x) & 0x7fffffffu) >> HIST2_BITS], 1);
    atomicAdd(&h[(__float_as_uint(b.y) & 0x7fffffffu) >> HIST2_BITS], 1);
    atomicAdd(&h[(__float_as_uint(b.z) & 0x7fffffffu) >> HIST2_BITS], 1);
    atomicAdd(&h[(__float_as_uint(b.w) & 0x7fffffffu) >> HIST2_BITS], 1);
  }
  if (j < NV) {
    float4 a = vec[j];
    atomicAdd(&h[(__float_as_uint(a.x) & 0x7fffffffu) >> HIST2_BITS], 1);
    atomicAdd(&h[(__float_as_uint(a.y) & 0x7fffffffu) >> HIST2_BITS], 1);
    atomicAdd(&h[(__float_as_uint(a.z) & 0x7fffffffu) >> HIST2_BITS], 1);
    atomicAdd(&h[(__float_as_uint(a.w) & 0x7fffffffu) >> HIST2_BITS], 1);
  }
  if (blockIdx.x == 0 && threadIdx.x == 0) {          // tail (N % 4)
    for (int i = NV << 2; i < N; ++i)
      atomicAdd(&h[(__float_as_uint(x[i]) & 0x7fffffffu) >> HIST2_BITS], 1);
  }
  __syncthreads();
  for (int i = threadIdx.x; i < HIST1_SIZE; i += 256) {
    int c = h[i];
    if (c) atomicAdd(&hist1[i], c);
  }
}

// ---------------- select median buckets, in-bucket ranks, conservative thrLo ----------------
__global__ void k_select(const int* __restrict__ hist1, long long k1, long long k2,
                         int* __restrict__ p) {
  __shared__ int part[256];
  __shared__ long long excl[256];
  __shared__ int b1s, b2s, cb1s, cb2s;
  int tid = threadIdx.x;
  const int chunk = HIST1_SIZE / 256;  // 32
  int base = tid * chunk;
  int s = 0;
  for (int w = 0; w < chunk; ++w) s += hist1[base + w];
  part[tid] = s;
  __syncthreads();
  if (tid == 0) {
    long long acc = 0;
    for (int i = 0; i < 256; ++i) { excl[i] = acc; acc += part[i]; }
  }
  __syncthreads();
  long long pre = excl[tid];
  if (pre <= k1 && k1 < pre + part[tid]) {
    long long acc = pre;
    for (int w = 0; w < chunk; ++w) {
      int c = hist1[base + w];
      if (k1 < acc + c) { b1s = base + w; cb1s = (int)(k1 - acc); break; }
      acc += c;
    }
  }
  if (pre <= k2 && k2 < pre + part[tid]) {
    long long acc = pre;
    for (int w = 0; w < chunk; ++w) {
      int c = hist1[base + w];
      if (k2 < acc + c) { b2s = base + w; cb2s = (int)(k2 - acc); break; }
      acc += c;
    }
  }
  __syncthreads();
  if (tid == 0) {
    p[P_B1] = b1s; p[P_B2] = b2s;
    p[P_R1] = cb1s; p[P_R2] = cb2s;          // ranks within bucket
    float lo1 = __uint_as_float((uint32_t)b1s << HIST2_BITS);
    float lo2 = __uint_as_float((uint32_t)b2s << HIST2_BITS);
    float mLo = 0.5f * (lo1 + lo2);
    p[P_THRLO] = __float_as_int((5.0f * mLo / 0.6745f) * 0.999f);
  }
}

// ---------------- pass 2: compact in-bucket values + candidates (no hist atomics) ----------------
__device__ inline void p2_elem(float f, int idx, int b1, int b2, float thrLo,
                               int* lbuf, int* lcnt,
                               int* listN, int* list, int* p, int* cand) {
  uint32_t u = __float_as_uint(f) & 0x7fffffffu;
  int top = (int)(u >> HIST2_BITS);
  bool in1 = (top == b1);
  bool in2 = (top == b2) && !in1;
  if (in1 || in2) {
    int val = (in2 ? (1 << HIST2_BITS) : 0) | (int)(u & LOW18_MASK);
    int id = atomicAdd(lcnt, 1);
    if (id < LBUF_CAP) lbuf[id] = val;
    else { int g = atomicAdd(&p[P_LISTN], 1); if (g < LIST_CAP) list[g] = val; }
  }
  if (__uint_as_float(u) > thrLo) {
    int id = atomicAdd(&p[P_CANDN], 1);
    if (id < CAND_CAP) cand[id] = idx;
  }
}

__global__ __launch_bounds__(256) void k_pass2(const float* __restrict__ x, int N,
                                               int* __restrict__ p,
                                               int* __restrict__ list,
                                               int* __restrict__ cand) {
  __shared__ int lbuf[LBUF_CAP];
  __shared__ int lcnt;
  __shared__ int lbase;
  if (threadIdx.x == 0) lcnt = 0;
  __syncthreads();
  int b1 = p[P_B1], b2 = p[P_B2];
  float thrLo = __int_as_float(p[P_THRLO]);
  int NV = N >> 2;
  int str = gridDim.x * 256;
  int j = blockIdx.x * 256 + threadIdx.x;
  const float4* vec = reinterpret_cast<const float4*>(x);
  for (; j + str < NV; j += 2 * str) {
    float4 a = vec[j];
    float4 b = vec[j + str];
    int ba = j << 2, bb = (j + str) << 2;
    p2_elem(a.x, ba + 0, b1, b2, thrLo, lbuf, &lcnt, 0, list, p, cand);
    p2_elem(a.y, ba + 1, b1, b2, thrLo, lbuf, &lcnt, 0, list, p, cand);
    p2_elem(a.z, ba + 2, b1, b2, thrLo, lbuf, &lcnt, 0, list, p, cand);
    p2_elem(a.w, ba + 3, b1, b2, thrLo, lbuf, &lcnt, 0, list, p, cand);
    p2_elem(b.x, bb + 0, b1, b2, thrLo, lbuf, &lcnt, 0, list, p, cand);
    p2_elem(b.y, bb + 1, b1, b2, thrLo, lbuf, &lcnt, 0, list, p, cand);
    p2_elem(b.z, bb + 2, b1, b2, thrLo, lbuf, &lcnt, 0, list, p, cand);
    p2_elem(b.w, bb + 3, b1, b2, thrLo, lbuf, &lcnt, 0, list, p, cand);
  }
  if (j < NV) {
    float4 a = vec[j];
    int ba = j << 2;
    p2_elem(a.x, ba + 0, b1, b2, thrLo, lbuf, &lcnt, 0, list, p, cand);
    p2_elem(a.y, ba + 1, b1, b2, thrLo, lbuf, &lcnt, 0, list, p, cand);
    p2_elem(a.z, ba + 2, b1, b2, thrLo, lbuf, &lcnt, 0, list, p, cand);
    p2_elem(a.w, ba + 3, b1, b2, thrLo, lbuf, &lcnt, 0, list, p, cand);
  }
  if (blockIdx.x == 0 && threadIdx.x == 0) {      // tail (N % 4)
    for (int i = NV << 2; i < N; ++i)
      p2_elem(x[i], i, b1, b2, thrLo, lbuf, &lcnt, 0, list, p, cand);
  }
  __syncthreads();
  int n = lcnt < LBUF_CAP ? lcnt : LBUF_CAP;
  if (threadIdx.x == 0) lbase = atomicAdd(&p[P_LISTN], n);
  __syncthreads();
  int base = lbase;
  for (int i = threadIdx.x; i < n; i += 256)
    if (base + i < LIST_CAP) list[base + i] = lbuf[i];
}

// ---------------- stage A: 1024-bin hist of list (per bucket tag) ----------------
__global__ __launch_bounds__(256) void k_histA(const int* __restrict__ list,
                                               const int* __restrict__ p,
                                               int* __restrict__ histA) {
  __shared__ int h[2048];
  for (int i = threadIdx.x; i < 2048; i += 256) h[i] = 0;
  __syncthreads();
  int n = p[P_LISTN]; if (n > LIST_CAP) n = LIST_CAP;
  int str = gridDim.x * 256;
  for (int i = blockIdx.x * 256 + threadIdx.x; i < n; i += str) {
    int v = list[i];
    int tag = (v >> HIST2_BITS) & 1;
    atomicAdd(&h[tag * 1024 + ((v >> 8) & 1023)], 1);
  }
  __syncthreads();
  for (int i = threadIdx.x; i < 2048; i += 256) {
    int c = h[i];
    if (c) atomicAdd(&histA[i], c);
  }
}

// ---------------- select stage-A bin per target ----------------
__global__ void k_selA(const int* __restrict__ histA, int* __restrict__ p) {
  __shared__ int sh[256];
  __shared__ int excl[256];
  int tid = threadIdx.x;
  int b1 = p[P_B1], b2 = p[P_B2];
  for (int tgt = 0; tgt < 2; ++tgt) {
    __syncthreads();
    int tag = (tgt == 1 && b1 != b2) ? 1 : 0;
    int rank = p[P_R1 + tgt];
    const int* h = histA + tag * 1024;
    int c0 = h[tid * 4], c1 = h[tid * 4 + 1], c2 = h[tid * 4 + 2], c3 = h[tid * 4 + 3];
    sh[tid] = c0 + c1 + c2 + c3;
    __syncthreads();
    if (tid == 0) {
      int a = 0;
      for (int i = 0; i < 256; ++i) { excl[i] = a; a += sh[i]; }
    }
    __syncthreads();
    int pre = excl[tid];
    if (pre <= rank && rank < pre + sh[tid]) {
      int a = pre;
      int cc[4] = {c0, c1, c2, c3};
      for (int w = 0; w < 4; ++w) {
        if (rank < a + cc[w]) {
          p[P_BINA0 + tgt] = tid * 4 + w;
          p[P_RA0 + tgt] = rank - a;
          if (tgt == 1) p[P_TAG1] = tag;
          break;
        }
        a += cc[w];
      }
    }
  }
}

// ---------------- stage B: 256-bin hist of low 8 bits for the selected bins ----------------
__global__ __launch_bounds__(256) void k_histB(const int* __restrict__ list,
                                               const int* __restrict__ p,
                                               int* __restrict__ histB) {
  __shared__ int h[512];
  if (threadIdx.x < 512) h[threadIdx.x] = 0;
  __syncthreads();
  int n = p[P_LISTN]; if (n > LIST_CAP) n = LIST_CAP;
  int bA0 = p[P_BINA0], bA1 = p[P_BINA1], tag1 = p[P_TAG1];
  int str = gridDim.x * 256;
  for (int i = blockIdx.x * 256 + threadIdx.x; i < n; i += str) {
    int v = list[i];
    int tag = (v >> HIST2_BITS) & 1;
    int ba = (v >> 8) & 1023;
    int lo = v & 255;
    if (tag == 0 && ba == bA0) atomicAdd(&h[lo], 1);
    if (tag == tag1 && ba == bA1) atomicAdd(&h[256 + lo], 1);
  }
  __syncthreads();
  if (threadIdx.x < 512) {
    int c = h[threadIdx.x];
    if (c) atomicAdd(&histB[threadIdx.x], c);
  }
}

// ---------------- final select + threshold ----------------
__global__ void k_thrF(const int* __restrict__ histB, int* __restrict__ p) {
  __shared__ int sh[256];
  __shared__ int excl[256];
  __shared__ float vres[2];
  int tid = threadIdx.x;
  int b1 = p[P_B1], b2 = p[P_B2];
  for (int tgt = 0; tgt < 2; ++tgt) {
    __syncthreads();
    const int* h = histB + tgt * 256;
    int rank = p[P_RA0 + tgt];
    int c = h[tid];
    sh[tid] = c;
    __syncthreads();
    if (tid == 0) {
      int a = 0;
      for (int i = 0; i < 256; ++i) { excl[i] = a; a += sh[i]; }
    }
    __syncthreads();
    int pre = excl[tid];
    if (pre <= rank && rank < pre + c) {
      int bkt = (tgt == 0) ? b1 : b2;
      uint32_t bits = ((uint32_t)bkt << HIST2_BITS) |
                      ((uint32_t)p[P_BINA0 + tgt] << 8) | (uint32_t)tid;
      vres[tgt] = __uint_as_float(bits);
    }
  }
  __syncthreads();
  if (tid == 0) {
    float med = 0.5f * (vres[0] + vres[1]);     // np.median: mean of two mid order stats
    p[P_THR] = __float_as_int((5.0f * med) / 0.6745f);  // reference f32 expression order
  }
}

// ---------------- finalize: pairs from candidates, windowed argmax, sort ----------------
__device__ static void isort(int* a, int n) {
  for (int i = 1; i < n; ++i) {
    int v = a[i]; int j = i - 1;
    while (j >= 0 && a[j] > v) { a[j + 1] = a[j]; --j; }
    a[j + 1] = v;
  }
}

__device__ inline void eval_pair(const float* __restrict__ x, int p, float thr,
                                 int* pe, int* px, int* ne, int* nx, int* cnt) {
  float a = x[p], b = x[p + 1];
  bool m0 = a > thr, m1 = b > thr;
  if (m0 != m1) {
    int id = atomicAdd(&cnt[m1 ? 0 : 1], 1);
    if (id < PAIR_CAP) (m1 ? pe : px)[id] = p;
  }
  bool q0 = (-a) > thr, q1 = (-b) > thr;       // exact ref form: v=-x, v>thr
  if (q0 != q1) {
    int id = atomicAdd(&cnt[q1 ? 2 : 3], 1);
    if (id < PAIR_CAP) (q1 ? ne : nx)[id] = p;
  }
}

__device__ inline int wave_argmax36(const float* __restrict__ x, int N, int sign,
                                    int e, int lane) {
  float val = -INFINITY;
  int wi = lane;
  if (lane < MAX_SPIKE) {
    int idx = e + lane; if (idx > N - 1) idx = N - 1;   // ref: clip(entry+w, 0, N-1)
    float v = x[idx];
    val = (sign < 0) ? -v : v;
  }
  for (int off = 32; off; off >>= 1) {                  // tie -> smaller w (first max)
    float ov = __shfl_xor(val, off);
    int owi = __shfl_xor(wi, off);
    if (ov > val || (ov == val && owi < wi)) { val = ov; wi = owi; }
  }
  return e + wi;
}

__device__ inline int proc_pol(const float* __restrict__ x, int N, int sign,
                               const int* eL, int nE, const int* xL, int nX,
                               int* pk, int tid) {
  int n = nE < nX ? nE : nX;
  int tot = 0;
  for (int t = 0; t < n; ++t) {
    int dur = xL[t] - eL[t];
    if (dur <= MAX_SPIKE) {                    // negative dur kept (ref semantics)
      int pp = wave_argmax36(x, N, sign, eL[t], tid);
      if (tot < PEAK_CAP && tid == 0) pk[tot] = pp;
      ++tot;
    }
  }
  if (tot > PEAK_CAP) tot = PEAK_CAP;
  if (tid == 0) isort(pk, tot);                // ref sorts peaks
  return tot;
}

__global__ void k_finalize(const float* __restrict__ x, int N,
                           int* __restrict__ p, int* __restrict__ cand,
                           int* __restrict__ peaksP, int* __restrict__ peaksN,
                           int* __restrict__ totals) {
  __shared__ int pe[PAIR_CAP], px[PAIR_CAP], ne[PAIR_CAP], nx[PAIR_CAP];
  __shared__ int cnt[4];
  __shared__ int pkP[PEAK_CAP], pkN[PEAK_CAP];
  __shared__ int nPk[2];
  int tid = threadIdx.x;                        // blockDim = 64 (one wave)
  float thr = __int_as_float(p[P_THR]);
  int nC = p[P_CANDN]; if (nC > CAND_CAP) nC = CAND_CAP;
  if (tid < 4) cnt[tid] = 0;
  __syncthreads();
  if (tid == 0) isort(cand, nC);                // sort candidate indices
  __syncthreads();
  // pair (p,p+1) processed exactly once: from candidate p (right pair),
  // or from candidate p+1 iff p not a candidate.
  for (int k = tid; k < nC; k += 64) {
    int c = cand[k];
    bool prevAdj = (k > 0) && (cand[k - 1] == c - 1);
    if (c > 0 && !prevAdj) eval_pair(x, c - 1, thr, pe, px, ne, nx, cnt);
    if (c <= N - 2) eval_pair(x, c, thr, pe, px, ne, nx, cnt);
  }
  __syncthreads();
  int nPE = min(cnt[0], PAIR_CAP), nPX = min(cnt[1], PAIR_CAP);
  int nNE = min(cnt[2], PAIR_CAP), nNX = min(cnt[3], PAIR_CAP);
  if (tid == 0) { isort(pe, nPE); isort(px, nPX); }
  else if (tid == 1) { isort(ne, nNE); isort(nx, nNX); }
  __syncthreads();
  int t0 = proc_pol(x, N, +1, pe, nPE, px, nPX, pkP, tid);
  int t1 = proc_pol(x, N, -1, ne, nNE, nx, nNX, pkN, tid);
  if (tid == 0) { nPk[0] = t0; nPk[1] = t1; totals[0] = t0; totals[1] = t1; }
  __syncthreads();
  for (int j = tid; j < nPk[0]; j += 64) peaksP[j] = pkP[j];
  for (int j = tid; j < nPk[1]; j += 64) peaksN[j] = pkN[j];
}

// d_out is a float32 buffer: [OUT_K pos idx][OUT_K neg idx][threshold], -1.0f pad.
__global__ __launch_bounds__(256) void k_fill(float* __restrict__ out, int OUT_K,
                                              const int* __restrict__ peaksP,
                                              const int* __restrict__ peaksN,
                                              const int* __restrict__ totals,
                                              const int* __restrict__ p) {
  int j = blockIdx.x * 256 + threadIdx.x;
  if (j >= 2 * OUT_K + 1) return;
  if (j < OUT_K) {
    out[j] = (j < totals[0]) ? (float)peaksP[j] : -1.0f;
  } else if (j < 2 * OUT_K) {
    int jj = j - OUT_K;
    out[j] = (jj < totals[1]) ? (float)peaksN[jj] : -1.0f;
  } else {
    out[j] = __int_as_float(p[P_THR]);
  }
}

extern "C" void kernel_launch(void* const* d_in, const int* in_sizes, int n_in,
                              void* d_out, int out_size, void* d_ws, size_t ws_size,
                              hipStream_t stream) {
  const float* x = (const float*)d_in[0];
  int N = in_sizes[0];
  float* out = (float*)d_out;
  char* ws = (char*)d_ws;

  int* hist1  = (int*)(ws + WS_HIST1);
  int* histA  = (int*)(ws + WS_HISTA);
  int* histB  = (int*)(ws + WS_HISTB);
  int* params = (int*)(ws + WS_PARAMS);
  int* totals = (int*)(ws + WS_TOTALS);
  int* cand   = (int*)(ws + WS_CAND);
  int* peaksP = (int*)(ws + WS_PEAKSP);
  int* peaksN = (int*)(ws + WS_PEAKSN);
  int* list   = (int*)(ws + WS_LIST);

  hipMemsetAsync(d_ws, 0, WS_ZERO_BYTES, stream);

  long long k1 = (long long)(N / 2) - 1;
  long long k2 = (long long)(N / 2);

  k_hist1<<<2048, 256, 0, stream>>>(x, N, hist1);
  k_select<<<1, 256, 0, stream>>>(hist1, k1, k2, params);
  k_pass2<<<2048, 256, 0, stream>>>(x, N, params, list, cand);
  k_histA<<<64, 256, 0, stream>>>(list, params, histA);
  k_selA<<<1, 256, 0, stream>>>(histA, params);
  k_histB<<<64, 256, 0, stream>>>(list, params, histB);
  k_thrF<<<1, 256, 0, stream>>>(histB, params);
  k_finalize<<<1, 64, 0, stream>>>(x, N, params, cand, peaksP, peaksN, totals);
  int OUT_K = (out_size - 1) / 2;  // 65536
  k_fill<<<(2 * OUT_K + 1 + 255) / 256, 256, 0, stream>>>(out, OUT_K, peaksP, peaksN,
                                                          totals, params);
}